// Round 1
// 4341.744 us; speedup vs baseline: 1.3304x; 1.3304x over previous
//
#include <hip/hip_runtime.h>
#include <math.h>

#define T_LEN 1000
#define BATCH 16
#define MEL   80
#define HID   512
#define NCLS  64
#define SL    8        // blocks per chain (8 x 512 threads)

__device__ __forceinline__ float fast_tanh(float x) {
    float e = __expf(2.0f * x);
    return 1.0f - 2.0f / (e + 1.0f);
}
__device__ __forceinline__ float fast_sigmoid(float x) {
    return 1.0f / (1.0f + __expf(-x));
}

// packed (value, epoch) 8B atom. Stored/loaded ONLY via __hip_atomic_{store,
// load} AGENT — the proven-safe primitive class (r7/r8: asm polls livelock).
__device__ __forceinline__ unsigned long long pack_pair(float v, unsigned e) {
    return ((unsigned long long)e << 32) | (unsigned long long)__float_as_uint(v);
}
__device__ __forceinline__ float pair_val(unsigned long long p) {
    return __uint_as_float((unsigned)(p & 0xffffffffull));
}
__device__ __forceinline__ unsigned pair_epoch(unsigned long long p) {
    return (unsigned)(p >> 32);
}

// one-shot LLC bulk load of 64 CONTIGUOUS floats (asm-defined => cannot be
// rematerialized => register-resident). NOT used in any spin loop.
__device__ __forceinline__ void llc_load16c(const float* base, float4 (&r)[16]) {
    asm volatile(
        "global_load_dwordx4 %0, %16, off sc0 sc1\n\t"
        "global_load_dwordx4 %1, %16, off offset:16 sc0 sc1\n\t"
        "global_load_dwordx4 %2, %16, off offset:32 sc0 sc1\n\t"
        "global_load_dwordx4 %3, %16, off offset:48 sc0 sc1\n\t"
        "global_load_dwordx4 %4, %16, off offset:64 sc0 sc1\n\t"
        "global_load_dwordx4 %5, %16, off offset:80 sc0 sc1\n\t"
        "global_load_dwordx4 %6, %16, off offset:96 sc0 sc1\n\t"
        "global_load_dwordx4 %7, %16, off offset:112 sc0 sc1\n\t"
        "global_load_dwordx4 %8, %16, off offset:128 sc0 sc1\n\t"
        "global_load_dwordx4 %9, %16, off offset:144 sc0 sc1\n\t"
        "global_load_dwordx4 %10, %16, off offset:160 sc0 sc1\n\t"
        "global_load_dwordx4 %11, %16, off offset:176 sc0 sc1\n\t"
        "global_load_dwordx4 %12, %16, off offset:192 sc0 sc1\n\t"
        "global_load_dwordx4 %13, %16, off offset:208 sc0 sc1\n\t"
        "global_load_dwordx4 %14, %16, off offset:224 sc0 sc1\n\t"
        "global_load_dwordx4 %15, %16, off offset:240 sc0 sc1\n\t"
        "s_waitcnt vmcnt(0)"
        : "=&v"(r[0]), "=&v"(r[1]), "=&v"(r[2]), "=&v"(r[3]),
          "=&v"(r[4]), "=&v"(r[5]), "=&v"(r[6]), "=&v"(r[7]),
          "=&v"(r[8]), "=&v"(r[9]), "=&v"(r[10]), "=&v"(r[11]),
          "=&v"(r[12]), "=&v"(r[13]), "=&v"(r[14]), "=&v"(r[15])
        : "v"(base)
        : "memory");
}

// K0: init partial-pair buffer to epoch 0 (never matches poll targets >= 1)
__global__ void k0_init(unsigned long long* part) {
    int i = blockIdx.x * 256 + threadIdx.x;
    if (i < BATCH * 2 * SL * HID) part[i] = 0ull;
}

// K1: per t: x_norm0 from feats, be0 = x_norm0 @ B0^T
__global__ __launch_bounds__(256) void k1_be0(const float* __restrict__ feats,
                                              const float* __restrict__ B0,
                                              float* __restrict__ be0) {
    const int t = blockIdx.x;
    const int tid = threadIdx.x;
    __shared__ float xf[BATCH][MEL];
    __shared__ float sc[BATCH];
    for (int idx = tid; idx < BATCH * MEL; idx += 256) {
        int b = idx / MEL, m = idx % MEL;
        xf[b][m] = feats[b * (T_LEN * MEL) + t * MEL + m];
    }
    __syncthreads();
    if (tid < BATCH) {
        float ss = 0.f;
        for (int m = 0; m < MEL; ++m) { float v = xf[tid][m]; ss += v * v; }
        sc[tid] = fmaxf(sqrtf(ss), 1e-6f);
    }
    __syncthreads();
    for (int idx = tid; idx < BATCH * MEL; idx += 256) {
        int b = idx / MEL, m = idx % MEL;
        float v = xf[b][m] / sc[b];
        xf[b][m] = fminf(fmaxf(v, -1.f), 1.f);
    }
    __syncthreads();
    for (int j = tid; j < HID; j += 256) {
        float acc[BATCH];
        #pragma unroll
        for (int b = 0; b < BATCH; ++b) acc[b] = 0.f;
        const float* brow = B0 + j * MEL;
        for (int k = 0; k < MEL; k += 4) {
            float4 w = *(const float4*)(brow + k);
            #pragma unroll
            for (int b = 0; b < BATCH; ++b) {
                float4 xv = *(const float4*)(&xf[b][k]);
                acc[b] += w.x * xv.x + w.y * xv.y + w.z * xv.z + w.w * xv.w;
            }
        }
        #pragma unroll
        for (int b = 0; b < BATCH; ++b)
            be0[(t * BATCH + b) * HID + j] = acc[b];
    }
}

// K2: per t: x_norm1 from be0, be1 = x_norm1 @ B1^T, store xs1
__global__ __launch_bounds__(256) void k2_be1(const float* __restrict__ be0,
                                              const float* __restrict__ B1,
                                              float* __restrict__ be1,
                                              float* __restrict__ xs1) {
    const int t = blockIdx.x;
    const int tid = threadIdx.x;
    __shared__ float xn[BATCH][HID];
    __shared__ float sc[BATCH];
    __shared__ float psum[BATCH][16];
    for (int idx = tid; idx < BATCH * HID; idx += 256) {
        int b = idx >> 9, k = idx & 511;
        xn[b][k] = be0[(t * BATCH + b) * HID + k];
    }
    __syncthreads();
    {
        int b = tid >> 4, l = tid & 15;
        float ss = 0.f;
        for (int k = l; k < HID; k += 16) { float v = xn[b][k]; ss += v * v; }
        psum[b][l] = ss;
    }
    __syncthreads();
    if (tid < BATCH) {
        float ss = 0.f;
        #pragma unroll
        for (int l = 0; l < 16; ++l) ss += psum[tid][l];
        float s = fmaxf(sqrtf(ss), 1e-6f);
        sc[tid] = s;
        xs1[t * BATCH + tid] = s;
    }
    __syncthreads();
    for (int idx = tid; idx < BATCH * HID; idx += 256) {
        int b = idx >> 9, k = idx & 511;
        float v = xn[b][k] / sc[b];
        xn[b][k] = fminf(fmaxf(v, -1.f), 1.f);
    }
    __syncthreads();
    for (int j = tid; j < HID; j += 256) {
        float acc[BATCH];
        #pragma unroll
        for (int b = 0; b < BATCH; ++b) acc[b] = 0.f;
        const float* brow = B1 + j * HID;
        for (int k = 0; k < HID; k += 4) {
            float4 w = *(const float4*)(brow + k);
            #pragma unroll
            for (int b = 0; b < BATCH; ++b) {
                float4 xv = *(const float4*)(&xn[b][k]);
                acc[b] += w.x * xv.x + w.y * xv.y + w.z * xv.z + w.w * xv.w;
            }
        }
        #pragma unroll
        for (int b = 0; b < BATCH; ++b)
            be1[(t * BATCH + b) * HID + j] = acc[b];
    }
}

// K3: sequential recurrence, ONE exchange per step.
//   Block s owns h slice [64s,64s+64) and NEVER exchanges h.
//   Phase 1 (k-split): partial dp[j] for ALL 512 j over local 64-deep k-slice,
//     published as 512 (value,epoch) pairs into the t&1 slot.
//   Exchange: each thread polls its j's 8 source pairs, sums -> full dp ->
//     full err vector reconstructed redundantly in every block (tanh/ssq local).
//   Phase 2 (j-split): ee[j] for own 64 j's from local err, gated h update.
//   Double-buffered slots make overwrite-before-read impossible (a producer
//   reaches slot p again only after all peers published t+1, which required
//   them to finish reading slot p at t).
__global__ __launch_bounds__(512, 1) void k3_fused(
    const float* __restrict__ be0, const float* __restrict__ be1,
    const float* __restrict__ xs1,
    const float* __restrict__ C1, const float* __restrict__ W1,
    const float* __restrict__ a1, const float* __restrict__ tau,
    const float* __restrict__ gam,
    float* __restrict__ h1s,
    unsigned long long* part)
{
    const int chain = blockIdx.x & 15;
    const int slice = blockIdx.x >> 4;        // 0..7
    const int tid = threadIdx.x;              // 0..511
    const int w = tid >> 6;                   // wave 0..7
    const int lane = tid & 63;
    const int jq = tid >> 3;                  // phase-2 output within slice 0..63
    const int kc = tid & 7;                   // phase-2 k-chunk 0..7
    const int j2 = slice * 64 + jq;           // phase-2 global output column
    const bool lead = (kc == 0);

    // 32 float4 = 128 regs of weights, asm-defined => register-resident
    // phase-1: C1[row=tid, cols 64*slice..+64)   (column-slice of C1)
    // phase-2: W1[row=j2,  cols 64*kc..+64)      (row-slice of W1)
    float4 wC[16], wW[16];
    llc_load16c(C1 + (size_t)tid * HID + slice * 64, wC);
    llc_load16c(W1 + (size_t)j2 * HID + kc * 64, wW);

    const float tauv = tau[0], gamv = gam[0];
    const float siga = fast_sigmoid(a1[j2]);

    unsigned long long* pc = part + (size_t)chain * (2 * SL * HID);

    __shared__ float h_s[64];                 // local h slice (broadcast reads)
    __shared__ float e_s[HID + 32];           // err, padded: idx + (idx>>6)*4
    __shared__ float sq_s[8];

    float hj = 0.f;                           // lead lanes: h for column j2
    if (tid < 64) h_s[tid] = 0.f;

    // t=0 streams (be0 full row per block: regular load, L2-shared on-XCD)
    float cur_be0 = be0[(size_t)chain * HID + tid];
    float cur_be1 = 0.f;
    if (lead) cur_be1 = __builtin_nontemporal_load(&be1[(size_t)chain * HID + j2]);
    float cur_xs = xs1[chain];
    __syncthreads();

    for (int t = 0; t < T_LEN; ++t) {
        // prefetch next step's streams (overlaps publish+poll)
        float nxt_be0 = 0.f, nxt_be1 = 0.f, nxt_xs = 0.f;
        if (t + 1 < T_LEN) {
            const size_t nrow = (size_t)((t + 1) * BATCH + chain) * HID;
            nxt_be0 = be0[nrow + tid];
            if (lead) nxt_be1 = __builtin_nontemporal_load(&be1[nrow + j2]);
            nxt_xs = xs1[(t + 1) * BATCH + chain];
        }
        const unsigned tag = (unsigned)(t + 1);
        unsigned long long* ps = pc + (size_t)(t & 1) * (SL * HID);

        // ---- phase 1: partial dp for row tid over local k-slice ----
        {
            float p0 = 0.f, p1 = 0.f, p2 = 0.f, p3 = 0.f;
            #pragma unroll
            for (int i = 0; i < 16; ++i) {
                float4 hv = *(const float4*)(h_s + 4 * i);   // broadcast
                p0 += wC[i].x * hv.x; p1 += wC[i].y * hv.y;
                p2 += wC[i].z * hv.z; p3 += wC[i].w * hv.w;
            }
            float dpp = (p0 + p1) + (p2 + p3);
            __hip_atomic_store(&ps[slice * HID + tid], pack_pair(dpp, tag),
                               __ATOMIC_RELAXED, __HIP_MEMORY_SCOPE_AGENT);
        }

        // ---- poll: 8 source partials for row tid, sum -> full dp ----
        float dp;
        {
            unsigned long long pv0, pv1, pv2, pv3, pv4, pv5, pv6, pv7;
            for (;;) {
                pv0 = __hip_atomic_load(&ps[0 * HID + tid], __ATOMIC_RELAXED, __HIP_MEMORY_SCOPE_AGENT);
                pv1 = __hip_atomic_load(&ps[1 * HID + tid], __ATOMIC_RELAXED, __HIP_MEMORY_SCOPE_AGENT);
                pv2 = __hip_atomic_load(&ps[2 * HID + tid], __ATOMIC_RELAXED, __HIP_MEMORY_SCOPE_AGENT);
                pv3 = __hip_atomic_load(&ps[3 * HID + tid], __ATOMIC_RELAXED, __HIP_MEMORY_SCOPE_AGENT);
                pv4 = __hip_atomic_load(&ps[4 * HID + tid], __ATOMIC_RELAXED, __HIP_MEMORY_SCOPE_AGENT);
                pv5 = __hip_atomic_load(&ps[5 * HID + tid], __ATOMIC_RELAXED, __HIP_MEMORY_SCOPE_AGENT);
                pv6 = __hip_atomic_load(&ps[6 * HID + tid], __ATOMIC_RELAXED, __HIP_MEMORY_SCOPE_AGENT);
                pv7 = __hip_atomic_load(&ps[7 * HID + tid], __ATOMIC_RELAXED, __HIP_MEMORY_SCOPE_AGENT);
                bool ok = (pair_epoch(pv0) == tag) & (pair_epoch(pv1) == tag)
                        & (pair_epoch(pv2) == tag) & (pair_epoch(pv3) == tag)
                        & (pair_epoch(pv4) == tag) & (pair_epoch(pv5) == tag)
                        & (pair_epoch(pv6) == tag) & (pair_epoch(pv7) == tag);
                if (__all(ok)) break;
                __builtin_amdgcn_s_sleep(1);
            }
            dp = ((pair_val(pv0) + pair_val(pv1)) + (pair_val(pv2) + pair_val(pv3)))
               + ((pair_val(pv4) + pair_val(pv5)) + (pair_val(pv6) + pair_val(pv7)));
        }

        // ---- full err vector local; stage padded for conflict-free phase 2 ----
        {
            float err = cur_be0 - fast_tanh(dp) * cur_xs;
            e_s[tid + (tid >> 6) * 4] = err;
            float sq = err * err;
            #pragma unroll
            for (int off = 32; off > 0; off >>= 1) sq += __shfl_down(sq, off, 64);
            if (lane == 0) sq_s[w] = sq;
        }
        __syncthreads();   // e_s + sq_s complete

        // ---- phase 2: ee = (err @ W1^T)[j2] over k-chunk, gated update ----
        {
            float ssT = ((sq_s[0] + sq_s[1]) + (sq_s[2] + sq_s[3]))
                      + ((sq_s[4] + sq_s[5]) + (sq_s[6] + sq_s[7]));
            const float* esb = e_s + kc * 68;
            float q0 = 0.f, q1 = 0.f, q2 = 0.f, q3 = 0.f;
            #pragma unroll
            for (int i = 0; i < 16; ++i) {
                float4 ev = *(const float4*)(esb + 4 * i);
                q0 += wW[i].x * ev.x; q1 += wW[i].y * ev.y;
                q2 += wW[i].z * ev.z; q3 += wW[i].w * ev.w;
            }
            float ee = (q0 + q1) + (q2 + q3);
            ee += __shfl_down(ee, 4, 8);
            ee += __shfl_down(ee, 2, 8);
            ee += __shfl_down(ee, 1, 8);
            if (lead) {
                float rel = fminf(sqrtf(ssT) / cur_xs, 4.0f);
                float s = fast_sigmoid((rel - tauv) / gamv);
                float input_h = hj * 0.2f + cur_be1 * 0.6f + ee * s * 0.2f;
                float g = s * siga;
                hj = hj * (1.f - g) + fast_tanh(input_h) * g;
                h_s[jq] = hj;
                __builtin_nontemporal_store(hj,
                    &h1s[(size_t)(t * BATCH + chain) * HID + j2]);
            }
        }
        __syncthreads();   // h_s ready for next step; e_s reads done

        cur_be0 = nxt_be0; cur_be1 = nxt_be1; cur_xs = nxt_xs;
    }
}

// K4: head matmul out[b,t,c] = [h1 || be1] @ head_w^T + head_b
__global__ __launch_bounds__(1024) void k4_head(const float* __restrict__ h1s,
                                                const float* __restrict__ be1,
                                                const float* __restrict__ head_w,
                                                const float* __restrict__ head_b,
                                                float* __restrict__ out) {
    const int t = blockIdx.x;
    const int tid = threadIdx.x;
    const int c = tid >> 4;
    const int b = tid & 15;
    const float* hw = head_w + c * (2 * HID);
    const float* x1 = h1s + (size_t)(t * BATCH + b) * HID;
    const float* x2 = be1 + (size_t)(t * BATCH + b) * HID;
    float acc0 = head_b[c], acc1 = 0.f;
    for (int k = 0; k < HID; k += 4) {
        float4 w = *(const float4*)(hw + k);
        float4 xv = *(const float4*)(x1 + k);
        acc0 += w.x * xv.x + w.y * xv.y + w.z * xv.z + w.w * xv.w;
    }
    for (int k = 0; k < HID; k += 4) {
        float4 w = *(const float4*)(hw + HID + k);
        float4 xv = *(const float4*)(x2 + k);
        acc1 += w.x * xv.x + w.y * xv.y + w.z * xv.z + w.w * xv.w;
    }
    out[b * (T_LEN * NCLS) + t * NCLS + c] = acc0 + acc1;
}

extern "C" void kernel_launch(void* const* d_in, const int* in_sizes, int n_in,
                              void* d_out, int out_size, void* d_ws, size_t ws_size,
                              hipStream_t stream) {
    const float* feats  = (const float*)d_in[0];
    const float* B0     = (const float*)d_in[2];
    const float* C1     = (const float*)d_in[7];
    const float* B1     = (const float*)d_in[8];
    const float* W1     = (const float*)d_in[9];
    const float* a1     = (const float*)d_in[10];
    const float* tau1   = (const float*)d_in[11];
    const float* gam1   = (const float*)d_in[12];
    const float* head_w = (const float*)d_in[13];
    const float* head_b = (const float*)d_in[14];
    float* out = (float*)d_out;

    float* be0 = (float*)d_ws;                          // T*B*HID
    float* be1 = be0 + (size_t)T_LEN * BATCH * HID;     // T*B*HID
    float* xs1 = be1 + (size_t)T_LEN * BATCH * HID;     // T*B
    float* h1s = xs1 + (size_t)T_LEN * BATCH;           // T*B*HID
    unsigned long long* part =
        (unsigned long long*)(h1s + (size_t)T_LEN * BATCH * HID);  // B*2*SL*HID u64

    hipLaunchKernelGGL(k0_init, dim3(512), dim3(256), 0, stream, part);
    hipLaunchKernelGGL(k1_be0, dim3(T_LEN), dim3(256), 0, stream, feats, B0, be0);
    hipLaunchKernelGGL(k2_be1, dim3(T_LEN), dim3(256), 0, stream, be0, B1, be1, xs1);
    hipLaunchKernelGGL(k3_fused, dim3(BATCH * SL), dim3(512), 0, stream,
                       be0, be1, xs1, C1, W1, a1, tau1, gam1, h1s, part);
    hipLaunchKernelGGL(k4_head, dim3(T_LEN), dim3(1024), 0, stream,
                       h1s, be1, head_w, head_b, out);
}